// Round 1
// baseline (23526.642 us; speedup 1.0000x reference)
//
#include <hip/hip_runtime.h>
#include <hip/hip_bf16.h>

// ---------------------------------------------------------------------------
// Seq2Seq LSTM (enc T=512, dec T=128, L=2, H=256, B=256), f32 I/O.
// Batch-split persistent kernel: 16 WGs x 1024 threads, one WG owns 16 batch
// rows for the whole 640-step recurrence -> zero cross-WG sync.
// Gates GEMM via mfma_f32_16x16x32_bf16; c-state in f32 registers.
// ---------------------------------------------------------------------------

namespace {

constexpr int T_CTXC = 512;
constexpr int T_PREDC = 128;
constexpr int NB = 16;     // batch rows per block
constexpr int K0 = 288;    // layer0 A/K: [h0(256) | x(8) | pad(24)]
constexpr int K1 = 512;    // layer1 A/K: [h0_new(256) | h1(256)]
constexpr int A0S = 296;   // LDS row stride (bank-decorrelating pad, 16B mult)
constexpr int A1S = 520;

constexpr size_t OFF_BIAS = 0;                                   // f32[4][1024]
constexpr size_t OFF_W0E = 16384;                                // bf16[1024][K0]
constexpr size_t OFF_W1E = OFF_W0E + (size_t)1024 * K0 * 2;      // bf16[1024][K1]
constexpr size_t OFF_W0D = OFF_W1E + (size_t)1024 * K1 * 2;
constexpr size_t OFF_W1D = OFF_W0D + (size_t)1024 * K0 * 2;
constexpr size_t WS_NEEDED = OFF_W1D + (size_t)1024 * K1 * 2;    // ~3.14 MB

typedef __attribute__((ext_vector_type(8))) short bf16x8;
typedef __attribute__((ext_vector_type(4))) float f32x4;

__device__ __forceinline__ float fsig(float x) {
    // 1/(1+e^-x); saturates correctly at +-inf (rcp(inf)=0)
    return __builtin_amdgcn_rcpf(1.0f + __expf(-x));
}
__device__ __forceinline__ float ftanh(float x) {
    // 1 - 2/(e^{2x}+1); exact saturation at +-inf
    return 1.0f - 2.0f * __builtin_amdgcn_rcpf(__expf(2.0f * x) + 1.0f);
}

__global__ void prep_kernel(
    const float* __restrict__ eWih0, const float* __restrict__ eWhh0,
    const float* __restrict__ ebih0, const float* __restrict__ ebhh0,
    const float* __restrict__ eWih1, const float* __restrict__ eWhh1,
    const float* __restrict__ ebih1, const float* __restrict__ ebhh1,
    const float* __restrict__ dWih0, const float* __restrict__ dWhh0,
    const float* __restrict__ dbih0, const float* __restrict__ dbhh0,
    const float* __restrict__ dWih1, const float* __restrict__ dWhh1,
    const float* __restrict__ dbih1, const float* __restrict__ dbhh1,
    unsigned char* __restrict__ ws)
{
    __hip_bfloat16* W0e = reinterpret_cast<__hip_bfloat16*>(ws + OFF_W0E);
    __hip_bfloat16* W1e = reinterpret_cast<__hip_bfloat16*>(ws + OFF_W1E);
    __hip_bfloat16* W0d = reinterpret_cast<__hip_bfloat16*>(ws + OFF_W0D);
    __hip_bfloat16* W1d = reinterpret_cast<__hip_bfloat16*>(ws + OFF_W1D);
    float* bias = reinterpret_cast<float*>(ws + OFF_BIAS);
    const int stride = gridDim.x * blockDim.x;
    const int tid0 = blockIdx.x * blockDim.x + threadIdx.x;

    // Wcat0 = [Whh0 | Wih0 | 0], row-major [1024][K0]
    for (int idx = tid0; idx < 1024 * K0; idx += stride) {
        int n = idx / K0, k = idx - n * K0;
        float ve, vd;
        if (k < 256)      { ve = eWhh0[n * 256 + k];       vd = dWhh0[n * 256 + k]; }
        else if (k < 264) { ve = eWih0[n * 8 + (k - 256)]; vd = dWih0[n * 8 + (k - 256)]; }
        else              { ve = 0.0f;                     vd = 0.0f; }
        W0e[idx] = __float2bfloat16(ve);
        W0d[idx] = __float2bfloat16(vd);
    }
    // Wcat1 = [Wih1 | Whh1], row-major [1024][K1]
    for (int idx = tid0; idx < 1024 * K1; idx += stride) {
        int n = idx >> 9, k = idx & 511;
        float ve = (k < 256) ? eWih1[n * 256 + k] : eWhh1[n * 256 + (k - 256)];
        float vd = (k < 256) ? dWih1[n * 256 + k] : dWhh1[n * 256 + (k - 256)];
        W1e[idx] = __float2bfloat16(ve);
        W1d[idx] = __float2bfloat16(vd);
    }
    for (int idx = tid0; idx < 1024; idx += stride) {
        bias[idx]        = ebih0[idx] + ebhh0[idx];
        bias[1024 + idx] = ebih1[idx] + ebhh1[idx];
        bias[2048 + idx] = dbih0[idx] + dbhh0[idx];
        bias[3072 + idx] = dbih1[idx] + dbhh1[idx];
    }
}

__global__ __launch_bounds__(1024, 1) void lstm_kernel(
    const float* __restrict__ xc, const float* __restrict__ yc,
    const float* __restrict__ xt, const float* __restrict__ yt,
    const float* __restrict__ fcW, const float* __restrict__ fcb,
    const unsigned char* __restrict__ ws, float* __restrict__ out)
{
    __shared__ __align__(16) __hip_bfloat16 A0[NB][A0S]; // [h0 | x | pad]
    __shared__ __align__(16) __hip_bfloat16 A1[NB][A1S]; // [h0_new | h1 | pad]
    __shared__ float fcw_s[256];
    __shared__ float h1f[NB][260];                       // f32 h1 for output dot

    const int tid = threadIdx.x;
    const int lane = tid & 63;
    const int wv = tid >> 6;          // wave 0..15
    const int bg = blockIdx.x;        // batch group 0..15
    const int mrow = lane & 15;       // A-frag M-row / C-frag N-col index
    const int kg = lane >> 4;         // k-group 0..3
    const int col = wv * 16 + mrow;   // owned h-column (0..255)

    const float* bias = reinterpret_cast<const float*>(ws + OFF_BIAS);
    const __hip_bfloat16* W0 = reinterpret_cast<const __hip_bfloat16*>(ws + OFF_W0E);
    const __hip_bfloat16* W1 = reinterpret_cast<const __hip_bfloat16*>(ws + OFF_W1E);

    // zero LDS (h=0, pads=0)
    const __hip_bfloat16 z16 = __float2bfloat16(0.0f);
    for (int i = tid; i < NB * A0S; i += 1024) (&A0[0][0])[i] = z16;
    for (int i = tid; i < NB * A1S; i += 1024) (&A1[0][0])[i] = z16;
    if (tid < 256) fcw_s[tid] = fcW[tid];
    __syncthreads();
    // stage encoder x for t=0 (after the zero-init barrier to avoid the race)
    if (tid < 128) {
        int r = tid >> 3, d = tid & 7, b = bg * NB + r;
        float v = (d < 7) ? xc[(size_t)(b * T_CTXC) * 7 + d] : yc[b * T_CTXC];
        A0[r][256 + d] = __float2bfloat16(v);
    }
    __syncthreads();

    float c0[4] = {0.f, 0.f, 0.f, 0.f};
    float c1[4] = {0.f, 0.f, 0.f, 0.f};
    float b0q[4], b1q[4];
    #pragma unroll
    for (int q = 0; q < 4; ++q) {
        b0q[q] = bias[q * 256 + col];
        b1q[q] = bias[1024 + q * 256 + col];
    }
    const float fcb_v = fcb[0];

    for (int t = 0; t < T_CTXC + T_PREDC; ++t) {
        const bool dec = (t >= T_CTXC);
        if (t == T_CTXC) {
            W0 = reinterpret_cast<const __hip_bfloat16*>(ws + OFF_W0D);
            W1 = reinterpret_cast<const __hip_bfloat16*>(ws + OFF_W1D);
            #pragma unroll
            for (int q = 0; q < 4; ++q) {
                b0q[q] = bias[2048 + q * 256 + col];
                b1q[q] = bias[3072 + q * 256 + col];
            }
        }

        // ---------------- layer 0: gates = [h0|x] @ Wcat0^T + b0 ----------------
        f32x4 acc0[4];
        #pragma unroll
        for (int q = 0; q < 4; ++q) { f32x4 v = {b0q[q], b0q[q], b0q[q], b0q[q]}; acc0[q] = v; }
        #pragma unroll
        for (int kc = 0; kc < K0 / 32; ++kc) {
            const bf16x8 a = *reinterpret_cast<const bf16x8*>(&A0[mrow][kc * 32 + kg * 8]);
            #pragma unroll
            for (int q = 0; q < 4; ++q) {
                const bf16x8 b = *reinterpret_cast<const bf16x8*>(
                    &W0[(size_t)(q * 256 + col) * K0 + kc * 32 + kg * 8]);
                acc0[q] = __builtin_amdgcn_mfma_f32_16x16x32_bf16(a, b, acc0[q], 0, 0, 0);
            }
        }
        __syncthreads();  // A0 reads done

        // layer0 cell update (c in regs), write h0_new -> A0 and A1
        #pragma unroll
        for (int r = 0; r < 4; ++r) {
            float gi = acc0[0][r], gf = acc0[1][r], gg = acc0[2][r], go = acc0[3][r];
            float cn = fsig(gf) * c0[r] + fsig(gi) * ftanh(gg);
            c0[r] = cn;
            float h = fsig(go) * ftanh(cn);
            __hip_bfloat16 hb = __float2bfloat16(h);
            int row = kg * 4 + r;
            A0[row][col] = hb;
            A1[row][col] = hb;
        }
        // stage x for step t+1 (A0 x-slot is free: this step's reads are done)
        if (tid < 128) {
            int r = tid >> 3, d = tid & 7, b = bg * NB + r;
            int tn = t + 1;
            if (tn < T_CTXC) {
                float v = (d < 7) ? xc[(size_t)(b * T_CTXC + tn) * 7 + d] : yc[b * T_CTXC + tn];
                A0[r][256 + d] = __float2bfloat16(v);
            } else if (tn == T_CTXC) {
                float v = (d < 7) ? xc[(size_t)(b * T_CTXC + T_CTXC - 1) * 7 + d] : 0.0f;
                A0[r][256 + d] = __float2bfloat16(v);
            } else if (tn < T_CTXC + T_PREDC) {
                int u = tn - T_CTXC - 1;
                float v = (d < 7) ? xt[(size_t)(b * T_PREDC + u) * 7 + d] : yt[b * T_PREDC + u];
                A0[r][256 + d] = __float2bfloat16(v);
            }
        }
        __syncthreads();  // h0_new + x visible

        // ---------------- layer 1: gates = [h0_new|h1] @ Wcat1^T + b1 ----------
        f32x4 acc1[4];
        #pragma unroll
        for (int q = 0; q < 4; ++q) { f32x4 v = {b1q[q], b1q[q], b1q[q], b1q[q]}; acc1[q] = v; }
        #pragma unroll
        for (int kc = 0; kc < K1 / 32; ++kc) {
            const bf16x8 a = *reinterpret_cast<const bf16x8*>(&A1[mrow][kc * 32 + kg * 8]);
            #pragma unroll
            for (int q = 0; q < 4; ++q) {
                const bf16x8 b = *reinterpret_cast<const bf16x8*>(
                    &W1[(size_t)(q * 256 + col) * K1 + kc * 32 + kg * 8]);
                acc1[q] = __builtin_amdgcn_mfma_f32_16x16x32_bf16(a, b, acc1[q], 0, 0, 0);
            }
        }
        __syncthreads();  // A1 reads done

        // layer1 cell update, write h1_new
        #pragma unroll
        for (int r = 0; r < 4; ++r) {
            float gi = acc1[0][r], gf = acc1[1][r], gg = acc1[2][r], go = acc1[3][r];
            float cn = fsig(gf) * c1[r] + fsig(gi) * ftanh(gg);
            c1[r] = cn;
            float h = fsig(go) * ftanh(cn);
            int row = kg * 4 + r;
            A1[row][256 + col] = __float2bfloat16(h);
            if (dec) h1f[row][col] = h;  // full-precision path for the output dot
        }

        if (dec) {
            __syncthreads();  // h1f visible
            if (tid < 256) {
                int r = tid >> 4, seg = tid & 15;
                float p = 0.0f;
                #pragma unroll
                for (int j = 0; j < 16; ++j)
                    p += h1f[r][seg * 16 + j] * fcw_s[seg * 16 + j];
                p += __shfl_xor(p, 1);
                p += __shfl_xor(p, 2);
                p += __shfl_xor(p, 4);
                p += __shfl_xor(p, 8);
                if (seg == 0)
                    out[(size_t)(bg * NB + r) * T_PREDC + (t - T_CTXC)] = p + fcb_v;
            }
        }
        // no barrier needed here: next step's readers are separated by >=1
        // barrier from this step's writers (see phase walk-through above)
    }
}

} // anonymous namespace

extern "C" void kernel_launch(void* const* d_in, const int* in_sizes, int n_in,
                              void* d_out, int out_size, void* d_ws, size_t ws_size,
                              hipStream_t stream)
{
    if (ws_size < WS_NEEDED) return;  // workspace too small (should not happen)

    const float* xc    = (const float*)d_in[0];
    const float* yc    = (const float*)d_in[1];
    const float* xt    = (const float*)d_in[2];
    const float* yt    = (const float*)d_in[3];
    // d_in[4]: teacher_forcing_prob == 1 (unused; decoder is fully teacher-forced)
    const float* eWih0 = (const float*)d_in[5];
    const float* eWhh0 = (const float*)d_in[6];
    const float* ebih0 = (const float*)d_in[7];
    const float* ebhh0 = (const float*)d_in[8];
    const float* eWih1 = (const float*)d_in[9];
    const float* eWhh1 = (const float*)d_in[10];
    const float* ebih1 = (const float*)d_in[11];
    const float* ebhh1 = (const float*)d_in[12];
    const float* dWih0 = (const float*)d_in[13];
    const float* dWhh0 = (const float*)d_in[14];
    const float* dbih0 = (const float*)d_in[15];
    const float* dbhh0 = (const float*)d_in[16];
    const float* dWih1 = (const float*)d_in[17];
    const float* dWhh1 = (const float*)d_in[18];
    const float* dbih1 = (const float*)d_in[19];
    const float* dbhh1 = (const float*)d_in[20];
    const float* fcW   = (const float*)d_in[21];
    const float* fcb   = (const float*)d_in[22];

    unsigned char* ws = (unsigned char*)d_ws;

    hipLaunchKernelGGL(prep_kernel, dim3(1024), dim3(256), 0, stream,
                       eWih0, eWhh0, ebih0, ebhh0, eWih1, eWhh1, ebih1, ebhh1,
                       dWih0, dWhh0, dbih0, dbhh0, dWih1, dWhh1, dbih1, dbhh1, ws);

    hipLaunchKernelGGL(lstm_kernel, dim3(16), dim3(1024), 0, stream,
                       xc, yc, xt, yt, fcW, fcb, (const unsigned char*)ws,
                       (float*)d_out);
}

// Round 2
// 3194.056 us; speedup vs baseline: 7.3658x; 7.3658x over previous
//
#include <hip/hip_runtime.h>
#include <hip/hip_bf16.h>
#include <stdint.h>

// ---------------------------------------------------------------------------
// Seq2Seq LSTM (enc T=512, dec T=128, L=2, H=256, B=256), f32 I/O.
// Round 2: N-split persistent kernel. 256 WGs = 16 batch-groups x 16
// column-slices; each WG holds its weight slice in VGPRs (13 bf16x8 MFMA
// B-fragments per lane). Per step, the 16 WGs of a batch group exchange
// 16x16 bf16 h-tiles through agent-scope atomics + monotone flags
// (parity-double-buffered). c-state in f32 registers; output dot in f32.
// ---------------------------------------------------------------------------

namespace {

constexpr int T_CTXC = 512;
constexpr int T_PRED = 128;
constexpr int TTOT   = T_CTXC + T_PRED;   // 640
constexpr int K0 = 288;    // layer0 K: [h0(256) | x(8) | pad(24)]
constexpr int K1 = 512;    // layer1 K: [h0_new(256) | h1(256)]
constexpr int A0S = 296;   // LDS row stride (16B multiple, bank-spreading)
constexpr int A1S = 264;   // A1 holds h1 only (256 cols)

constexpr size_t OFF_BIAS  = 0;                                  // f32[4][1024]
constexpr size_t OFF_W0E   = 16384;                              // bf16[1024][K0]
constexpr size_t OFF_W1E   = OFF_W0E + (size_t)1024 * K0 * 2;    // bf16[1024][K1]
constexpr size_t OFF_W0D   = OFF_W1E + (size_t)1024 * K1 * 2;
constexpr size_t OFF_W1D   = OFF_W0D + (size_t)1024 * K0 * 2;
constexpr size_t OFF_FLAG0 = OFF_W1D + (size_t)1024 * K1 * 2;    // u32[16][16]
constexpr size_t OFF_FLAG1 = OFF_FLAG0 + 1024;                   // u32[16][16]
constexpr size_t OFF_H0    = OFF_FLAG1 + 1024;                   // u32[2][16][2048]
constexpr size_t OFF_H1    = OFF_H0 + (size_t)2 * 16 * 2048 * 4;
constexpr size_t OFF_OPART = OFF_H1 + (size_t)2 * 16 * 2048 * 4; // f32[16][256*128]
constexpr size_t WS_NEEDED = OFF_OPART + (size_t)16 * 256 * 128 * 4;  // ~5.4 MB

typedef __attribute__((ext_vector_type(8))) short bf16x8;
typedef __attribute__((ext_vector_type(4))) float f32x4;

__device__ __forceinline__ float fsig(float x) {
    return __builtin_amdgcn_rcpf(1.0f + __expf(-x));
}
__device__ __forceinline__ float ftanh(float x) {
    return 1.0f - 2.0f * __builtin_amdgcn_rcpf(__expf(2.0f * x) + 1.0f);
}

__global__ void prep_kernel(
    const float* __restrict__ eWih0, const float* __restrict__ eWhh0,
    const float* __restrict__ ebih0, const float* __restrict__ ebhh0,
    const float* __restrict__ eWih1, const float* __restrict__ eWhh1,
    const float* __restrict__ ebih1, const float* __restrict__ ebhh1,
    const float* __restrict__ dWih0, const float* __restrict__ dWhh0,
    const float* __restrict__ dbih0, const float* __restrict__ dbhh0,
    const float* __restrict__ dWih1, const float* __restrict__ dWhh1,
    const float* __restrict__ dbih1, const float* __restrict__ dbhh1,
    unsigned char* __restrict__ ws)
{
    __hip_bfloat16* W0e = reinterpret_cast<__hip_bfloat16*>(ws + OFF_W0E);
    __hip_bfloat16* W1e = reinterpret_cast<__hip_bfloat16*>(ws + OFF_W1E);
    __hip_bfloat16* W0d = reinterpret_cast<__hip_bfloat16*>(ws + OFF_W0D);
    __hip_bfloat16* W1d = reinterpret_cast<__hip_bfloat16*>(ws + OFF_W1D);
    float* bias = reinterpret_cast<float*>(ws + OFF_BIAS);
    uint32_t* fl = reinterpret_cast<uint32_t*>(ws + OFF_FLAG0);
    const int stride = gridDim.x * blockDim.x;
    const int tid0 = blockIdx.x * blockDim.x + threadIdx.x;

    // Wcat0 = [Whh0 | Wih0 | 0], row-major [1024][K0]
    for (int idx = tid0; idx < 1024 * K0; idx += stride) {
        int n = idx / K0, k = idx - n * K0;
        float ve, vd;
        if (k < 256)      { ve = eWhh0[n * 256 + k];       vd = dWhh0[n * 256 + k]; }
        else if (k < 264) { ve = eWih0[n * 8 + (k - 256)]; vd = dWih0[n * 8 + (k - 256)]; }
        else              { ve = 0.0f;                     vd = 0.0f; }
        W0e[idx] = __float2bfloat16(ve);
        W0d[idx] = __float2bfloat16(vd);
    }
    // Wcat1 = [Wih1 | Whh1], row-major [1024][K1]
    for (int idx = tid0; idx < 1024 * K1; idx += stride) {
        int n = idx >> 9, k = idx & 511;
        float ve = (k < 256) ? eWih1[n * 256 + k] : eWhh1[n * 256 + (k - 256)];
        float vd = (k < 256) ? dWih1[n * 256 + k] : dWhh1[n * 256 + (k - 256)];
        W1e[idx] = __float2bfloat16(ve);
        W1d[idx] = __float2bfloat16(vd);
    }
    for (int idx = tid0; idx < 1024; idx += stride) {
        bias[idx]        = ebih0[idx] + ebhh0[idx];
        bias[1024 + idx] = ebih1[idx] + ebhh1[idx];
        bias[2048 + idx] = dbih0[idx] + dbhh0[idx];
        bias[3072 + idx] = dbih1[idx] + dbhh1[idx];
    }
    // zero sync flags (ws is re-poisoned 0xAA before every launch)
    for (int idx = tid0; idx < 512; idx += stride) fl[idx] = 0;
}

__global__ __launch_bounds__(512, 2) void lstm_kernel(
    const float* __restrict__ xc, const float* __restrict__ yc,
    const float* __restrict__ xt, const float* __restrict__ yt,
    const float* __restrict__ fcW, unsigned char* __restrict__ ws)
{
    __shared__ __align__(16) __hip_bfloat16 A0[16][A0S]; // [h0 | x | pad]
    __shared__ __align__(16) __hip_bfloat16 A1[16][A1S]; // [h1]
    __shared__ float gsm[2][4][16][16];                  // [khalf][quad][row][col]

    const int tid  = threadIdx.x;
    const int lane = tid & 63;
    const int wv   = tid >> 6;      // 0..7
    const int q    = wv & 3;        // gate quadrant (i,f,g,o)
    const int kh   = wv >> 2;       // K-half
    const int l15  = lane & 15;     // MFMA A-row (batch) / B-row (gate col)
    const int kg   = lane >> 4;     // k-group
    const int bg   = blockIdx.x >> 4;   // batch group 0..15
    const int ns   = blockIdx.x & 15;   // column slice 0..15

    const float* bias = (const float*)(ws + OFF_BIAS);
    uint32_t* flag0 = (uint32_t*)(ws + OFF_FLAG0) + bg * 16;
    uint32_t* flag1 = (uint32_t*)(ws + OFF_FLAG1) + bg * 16;
    uint32_t* H0_32 = (uint32_t*)(ws + OFF_H0);
    uint32_t* H1_32 = (uint32_t*)(ws + OFF_H1);
    uint64_t* H0_64 = (uint64_t*)(ws + OFF_H0);
    uint64_t* H1_64 = (uint64_t*)(ws + OFF_H1);
    float* opart = (float*)(ws + OFF_OPART);

    // ---- init LDS (h0(-1)=0, h1(-1)=0, pads=0) ----
    const __hip_bfloat16 z16 = __float2bfloat16(0.0f);
    for (int i = tid; i < 16 * A0S; i += 512) (&A0[0][0])[i] = z16;
    for (int i = tid; i < 16 * A1S; i += 512) (&A1[0][0])[i] = z16;
    __syncthreads();
    if (tid < 128) {   // stage x(0)
        int r = tid >> 3, d = tid & 7, b = bg * 16 + r;
        float v = (d < 7) ? xc[(size_t)(b * T_CTXC) * 7 + d] : yc[b * T_CTXC];
        A0[r][256 + d] = __float2bfloat16(v);
    }

    // ---- weight slice in VGPRs: 13 B-fragments per lane ----
    bf16x8 w0f[5], w1f[8];
    const int wrow = q * 256 + ns * 16 + l15;
    auto load_w = [&](const __hip_bfloat16* W0, const __hip_bfloat16* W1) {
        const __hip_bfloat16* p0 = W0 + (size_t)wrow * K0 + kg * 8;
        const __hip_bfloat16* p1 = W1 + (size_t)wrow * K1 + kg * 8;
        if (kh == 0) {
            #pragma unroll
            for (int f = 0; f < 4; ++f) w0f[f] = *reinterpret_cast<const bf16x8*>(p0 + f * 32);
            #pragma unroll
            for (int f = 0; f < 8; ++f) w1f[f] = *reinterpret_cast<const bf16x8*>(p1 + f * 32);
        } else {
            #pragma unroll
            for (int f = 0; f < 5; ++f) w0f[f] = *reinterpret_cast<const bf16x8*>(p0 + (4 + f) * 32);
            #pragma unroll
            for (int f = 0; f < 8; ++f) w1f[f] = *reinterpret_cast<const bf16x8*>(p1 + (8 + f) * 32);
        }
    };
    load_w((const __hip_bfloat16*)(ws + OFF_W0E), (const __hip_bfloat16*)(ws + OFF_W1E));

    // ---- per-cell-thread state (tid < 256: one (batch row, h col) each) ----
    const int crow = tid >> 4;
    const int ccol = tid & 15;
    const int gcol = ns * 16 + ccol;
    float c0v = 0.f, c1v = 0.f;
    float b0r[4] = {0,0,0,0}, b1r[4] = {0,0,0,0}, fcw_r = 0.f;
    if (tid < 256) {
        #pragma unroll
        for (int qq = 0; qq < 4; ++qq) {
            b0r[qq] = bias[qq * 256 + gcol];
            b1r[qq] = bias[1024 + qq * 256 + gcol];
        }
        fcw_r = fcW[gcol];
    }
    __syncthreads();

    for (int t = 0; t < TTOT; ++t) {
        if (t == T_CTXC) {   // switch to decoder weights/biases
            load_w((const __hip_bfloat16*)(ws + OFF_W0D), (const __hip_bfloat16*)(ws + OFF_W1D));
            if (tid < 256) {
                #pragma unroll
                for (int qq = 0; qq < 4; ++qq) {
                    b0r[qq] = bias[2048 + qq * 256 + gcol];
                    b1r[qq] = bias[3072 + qq * 256 + gcol];
                }
            }
        }
        const int par = t & 1;
        const size_t hbase32 = (size_t)(par * 16 + bg) * 2048;
        const size_t hbase64 = (size_t)(par * 16 + bg) * 1024;

        // ---- phase 1: layer0 GEMM (A0 x weight-regs) ----
        {
            f32x4 acc = {0.f, 0.f, 0.f, 0.f};
            if (kh == 0) {
                #pragma unroll
                for (int f = 0; f < 4; ++f) {
                    bf16x8 a = *reinterpret_cast<const bf16x8*>(&A0[l15][f * 32 + kg * 8]);
                    acc = __builtin_amdgcn_mfma_f32_16x16x32_bf16(a, w0f[f], acc, 0, 0, 0);
                }
            } else {
                #pragma unroll
                for (int f = 0; f < 5; ++f) {
                    bf16x8 a = *reinterpret_cast<const bf16x8*>(&A0[l15][(4 + f) * 32 + kg * 8]);
                    acc = __builtin_amdgcn_mfma_f32_16x16x32_bf16(a, w0f[f], acc, 0, 0, 0);
                }
            }
            #pragma unroll
            for (int r = 0; r < 4; ++r) gsm[kh][q][kg * 4 + r][l15] = acc[r];
        }
        __syncthreads();

        // ---- phase 2: cell0 update + publish h0 slice ----
        if (tid < 256) {
            float gi = gsm[0][0][crow][ccol] + gsm[1][0][crow][ccol] + b0r[0];
            float gf = gsm[0][1][crow][ccol] + gsm[1][1][crow][ccol] + b0r[1];
            float gg = gsm[0][2][crow][ccol] + gsm[1][2][crow][ccol] + b0r[2];
            float go = gsm[0][3][crow][ccol] + gsm[1][3][crow][ccol] + b0r[3];
            c0v = fsig(gf) * c0v + fsig(gi) * ftanh(gg);
            float h = fsig(go) * ftanh(c0v);
            __hip_bfloat16 hb = __float2bfloat16(h);
            unsigned short hbits; __builtin_memcpy(&hbits, &hb, 2);
            uint32_t hu = hbits;
            uint32_t pr = (uint32_t)__shfl_xor((int)hu, 1);
            if ((ccol & 1) == 0) {
                uint32_t v = (hu & 0xffffu) | (pr << 16);
                __hip_atomic_store(&H0_32[hbase32 + crow * 128 + (gcol >> 1)], v,
                                   __ATOMIC_RELAXED, __HIP_MEMORY_SCOPE_AGENT);
            }
        }
        asm volatile("s_waitcnt vmcnt(0)" ::: "memory");  // slice stores complete
        __syncthreads();
        if (tid == 0)
            __hip_atomic_store(&flag0[ns], (uint32_t)(t + 1),
                               __ATOMIC_RELAXED, __HIP_MEMORY_SCOPE_AGENT);

        // ---- phase 3: stage x(t+1), poll peers, gather h0(t) -> A0 ----
        {
            int tn = t + 1;
            if (tid < 128 && tn < TTOT) {
                int r = tid >> 3, d = tid & 7, b = bg * 16 + r;
                float v;
                if (tn < T_CTXC)       v = (d < 7) ? xc[(size_t)(b * T_CTXC + tn) * 7 + d] : yc[b * T_CTXC + tn];
                else if (tn == T_CTXC) v = (d < 7) ? xc[(size_t)(b * T_CTXC + T_CTXC - 1) * 7 + d] : 0.0f;
                else { int u = tn - T_CTXC - 1;
                       v = (d < 7) ? xt[(size_t)(b * T_PRED + u) * 7 + d] : yt[b * T_PRED + u]; }
                A0[r][256 + d] = __float2bfloat16(v);
            }
        }
        if (tid < 16) {
            while (__hip_atomic_load(&flag0[tid], __ATOMIC_RELAXED, __HIP_MEMORY_SCOPE_AGENT)
                   < (uint32_t)(t + 1))
                __builtin_amdgcn_s_sleep(1);
        }
        __syncthreads();
        {
            uint64_t d0 = __hip_atomic_load(&H0_64[hbase64 + tid * 2 + 0],
                                            __ATOMIC_RELAXED, __HIP_MEMORY_SCOPE_AGENT);
            uint64_t d1 = __hip_atomic_load(&H0_64[hbase64 + tid * 2 + 1],
                                            __ATOMIC_RELAXED, __HIP_MEMORY_SCOPE_AGENT);
            int row = tid >> 5, c0i = (tid & 31) * 8;
            uint4 v = make_uint4((uint32_t)d0, (uint32_t)(d0 >> 32),
                                 (uint32_t)d1, (uint32_t)(d1 >> 32));
            *reinterpret_cast<uint4*>(&A0[row][c0i]) = v;
        }
        __syncthreads();

        // ---- phase 4: layer1 GEMM (kh0: h0-part from A0; kh1: h1-part from A1) ----
        {
            f32x4 acc = {0.f, 0.f, 0.f, 0.f};
            if (kh == 0) {
                #pragma unroll
                for (int f = 0; f < 8; ++f) {
                    bf16x8 a = *reinterpret_cast<const bf16x8*>(&A0[l15][f * 32 + kg * 8]);
                    acc = __builtin_amdgcn_mfma_f32_16x16x32_bf16(a, w1f[f], acc, 0, 0, 0);
                }
            } else {
                #pragma unroll
                for (int f = 0; f < 8; ++f) {
                    bf16x8 a = *reinterpret_cast<const bf16x8*>(&A1[l15][f * 32 + kg * 8]);
                    acc = __builtin_amdgcn_mfma_f32_16x16x32_bf16(a, w1f[f], acc, 0, 0, 0);
                }
            }
            #pragma unroll
            for (int r = 0; r < 4; ++r) gsm[kh][q][kg * 4 + r][l15] = acc[r];
        }
        __syncthreads();

        // ---- phase 5: cell1 update + publish h1 slice + output partial ----
        if (tid < 256) {
            float gi = gsm[0][0][crow][ccol] + gsm[1][0][crow][ccol] + b1r[0];
            float gf = gsm[0][1][crow][ccol] + gsm[1][1][crow][ccol] + b1r[1];
            float gg = gsm[0][2][crow][ccol] + gsm[1][2][crow][ccol] + b1r[2];
            float go = gsm[0][3][crow][ccol] + gsm[1][3][crow][ccol] + b1r[3];
            c1v = fsig(gf) * c1v + fsig(gi) * ftanh(gg);
            float h = fsig(go) * ftanh(c1v);
            __hip_bfloat16 hb = __float2bfloat16(h);
            unsigned short hbits; __builtin_memcpy(&hbits, &hb, 2);
            uint32_t hu = hbits;
            uint32_t pr = (uint32_t)__shfl_xor((int)hu, 1);
            if ((ccol & 1) == 0) {
                uint32_t v = (hu & 0xffffu) | (pr << 16);
                __hip_atomic_store(&H1_32[hbase32 + crow * 128 + (gcol >> 1)], v,
                                   __ATOMIC_RELAXED, __HIP_MEMORY_SCOPE_AGENT);
            }
            if (t >= T_CTXC) {   // f32 output partial (no bf16 rounding on this path)
                float p = h * fcw_r;
                p += __shfl_xor(p, 1);
                p += __shfl_xor(p, 2);
                p += __shfl_xor(p, 4);
                p += __shfl_xor(p, 8);
                if (ccol == 0)
                    opart[(size_t)ns * (256 * T_PRED)
                          + (size_t)(bg * 16 + crow) * T_PRED + (t - T_CTXC)] = p;
            }
        }
        asm volatile("s_waitcnt vmcnt(0)" ::: "memory");
        __syncthreads();
        if (tid == 0)
            __hip_atomic_store(&flag1[ns], (uint32_t)(t + 1),
                               __ATOMIC_RELAXED, __HIP_MEMORY_SCOPE_AGENT);

        // ---- phase 6: poll peers, gather h1(t) -> A1 ----
        if (tid < 16) {
            while (__hip_atomic_load(&flag1[tid], __ATOMIC_RELAXED, __HIP_MEMORY_SCOPE_AGENT)
                   < (uint32_t)(t + 1))
                __builtin_amdgcn_s_sleep(1);
        }
        __syncthreads();
        {
            uint64_t d0 = __hip_atomic_load(&H1_64[hbase64 + tid * 2 + 0],
                                            __ATOMIC_RELAXED, __HIP_MEMORY_SCOPE_AGENT);
            uint64_t d1 = __hip_atomic_load(&H1_64[hbase64 + tid * 2 + 1],
                                            __ATOMIC_RELAXED, __HIP_MEMORY_SCOPE_AGENT);
            int row = tid >> 5, c0i = (tid & 31) * 8;
            uint4 v = make_uint4((uint32_t)d0, (uint32_t)(d0 >> 32),
                                 (uint32_t)d1, (uint32_t)(d1 >> 32));
            *reinterpret_cast<uint4*>(&A1[row][c0i]) = v;
        }
        __syncthreads();
    }
}

__global__ void out_kernel(const float* __restrict__ fcb,
                           const unsigned char* __restrict__ ws,
                           float* __restrict__ out)
{
    int i = blockIdx.x * blockDim.x + threadIdx.x;
    if (i >= 256 * T_PRED) return;
    const float* op = (const float*)(ws + OFF_OPART);
    float s = fcb[0];
    #pragma unroll
    for (int j = 0; j < 16; ++j) s += op[(size_t)j * (256 * T_PRED) + i];
    out[i] = s;
}

} // anonymous namespace

extern "C" void kernel_launch(void* const* d_in, const int* in_sizes, int n_in,
                              void* d_out, int out_size, void* d_ws, size_t ws_size,
                              hipStream_t stream)
{
    if (ws_size < WS_NEEDED) return;  // workspace too small (fails visibly)

    const float* xc    = (const float*)d_in[0];
    const float* yc    = (const float*)d_in[1];
    const float* xt    = (const float*)d_in[2];
    const float* yt    = (const float*)d_in[3];
    // d_in[4]: teacher_forcing_prob == 1 (decoder fully teacher-forced)
    const float* eWih0 = (const float*)d_in[5];
    const float* eWhh0 = (const float*)d_in[6];
    const float* ebih0 = (const float*)d_in[7];
    const float* ebhh0 = (const float*)d_in[8];
    const float* eWih1 = (const float*)d_in[9];
    const float* eWhh1 = (const float*)d_in[10];
    const float* ebih1 = (const float*)d_in[11];
    const float* ebhh1 = (const float*)d_in[12];
    const float* dWih0 = (const float*)d_in[13];
    const float* dWhh0 = (const float*)d_in[14];
    const float* dbih0 = (const float*)d_in[15];
    const float* dbhh0 = (const float*)d_in[16];
    const float* dWih1 = (const float*)d_in[17];
    const float* dWhh1 = (const float*)d_in[18];
    const float* dbih1 = (const float*)d_in[19];
    const float* dbhh1 = (const float*)d_in[20];
    const float* fcW   = (const float*)d_in[21];
    const float* fcb   = (const float*)d_in[22];

    unsigned char* wsb = (unsigned char*)d_ws;

    hipLaunchKernelGGL(prep_kernel, dim3(1024), dim3(256), 0, stream,
                       eWih0, eWhh0, ebih0, ebhh0, eWih1, eWhh1, ebih1, ebhh1,
                       dWih0, dWhh0, dbih0, dbhh0, dWih1, dWhh1, dbih1, dbhh1, wsb);

    // all 256 WGs must be co-resident (cross-WG flag waits) -> cooperative launch
    void* kargs[] = { (void*)&xc, (void*)&yc, (void*)&xt, (void*)&yt,
                      (void*)&fcW, (void*)&wsb };
    hipError_t ce = hipLaunchCooperativeKernel(lstm_kernel, dim3(256), dim3(512),
                                               kargs, 0, stream);
    if (ce != hipSuccess) {
        // fallback: plain launch (256 WGs x 8 waves x ~35KB LDS fit 1/CU on 256 CUs)
        hipLaunchKernelGGL(lstm_kernel, dim3(256), dim3(512), 0, stream,
                           xc, yc, xt, yt, fcW, wsb);
    }

    hipLaunchKernelGGL(out_kernel, dim3((256 * T_PRED + 255) / 256), dim3(256), 0, stream,
                       fcb, (const unsigned char*)wsb, (float*)d_out);
}

// Round 5
// 2937.572 us; speedup vs baseline: 8.0089x; 1.0873x over previous
//
#include <hip/hip_runtime.h>
#include <hip/hip_bf16.h>
#include <stdint.h>

// ---------------------------------------------------------------------------
// Seq2Seq LSTM (enc T=512, dec T=128, L=2, H=256, B=256), f32 I/O.
// Round 3 design (third submission; rounds 3-4 benches lost to GPU-broker
// capacity timeouts, never executed):
// N-split persistent kernel with ONE exchange per step.
// 256 WGs = 16 batch-groups x 16 column-slices; weight slices in VGPRs.
// Per iteration i: gather {h0(i), h1(i-1)} (single flag), compute layer1(i)
// AND layer0(i+1) back-to-back, publish {h0(i+1), h1(i)}, single flag.
// Output partials atomicAdd'ed straight into d_out (memset to 0 first).
// ---------------------------------------------------------------------------

namespace {

constexpr int T_CTXC = 512;
constexpr int T_PRED = 128;
constexpr int TTOT   = T_CTXC + T_PRED;   // 640
constexpr int K0 = 288;    // layer0 K: [h0(256) | x(8) | pad(24)]
constexpr int HAS = 296;   // LDS row stride for HA (h0 | x | pad)
constexpr int HBS = 264;   // LDS row stride for HB (h1)

constexpr size_t OFF_BIAS = 0;                                   // f32[4][1024]
constexpr size_t OFF_W0E  = 16384;                               // bf16[1024][K0]
constexpr size_t OFF_W1E  = OFF_W0E + (size_t)1024 * K0 * 2;
constexpr size_t OFF_W0D  = OFF_W1E + (size_t)1024 * 512 * 2;
constexpr size_t OFF_W1D  = OFF_W0D + (size_t)1024 * K0 * 2;
constexpr size_t OFF_FLAG = OFF_W1D + (size_t)1024 * 512 * 2;    // u32[16][16]
constexpr size_t OFF_H    = OFF_FLAG + 1024;                     // u32[2][16][32][128]
constexpr size_t WS_NEEDED = OFF_H + (size_t)2 * 16 * 32 * 128 * 4;  // ~3.82 MB

typedef __attribute__((ext_vector_type(8))) short bf16x8;
typedef __attribute__((ext_vector_type(4))) float f32x4;

__device__ __forceinline__ float fsig(float x) {
    return __builtin_amdgcn_rcpf(1.0f + __expf(-x));
}
__device__ __forceinline__ float ftanh(float x) {
    return 1.0f - 2.0f * __builtin_amdgcn_rcpf(__expf(2.0f * x) + 1.0f);
}

__global__ void prep_kernel(
    const float* __restrict__ eWih0, const float* __restrict__ eWhh0,
    const float* __restrict__ ebih0, const float* __restrict__ ebhh0,
    const float* __restrict__ eWih1, const float* __restrict__ eWhh1,
    const float* __restrict__ ebih1, const float* __restrict__ ebhh1,
    const float* __restrict__ dWih0, const float* __restrict__ dWhh0,
    const float* __restrict__ dbih0, const float* __restrict__ dbhh0,
    const float* __restrict__ dWih1, const float* __restrict__ dWhh1,
    const float* __restrict__ dbih1, const float* __restrict__ dbhh1,
    unsigned char* __restrict__ ws)
{
    __hip_bfloat16* W0e = reinterpret_cast<__hip_bfloat16*>(ws + OFF_W0E);
    __hip_bfloat16* W1e = reinterpret_cast<__hip_bfloat16*>(ws + OFF_W1E);
    __hip_bfloat16* W0d = reinterpret_cast<__hip_bfloat16*>(ws + OFF_W0D);
    __hip_bfloat16* W1d = reinterpret_cast<__hip_bfloat16*>(ws + OFF_W1D);
    float* bias = reinterpret_cast<float*>(ws + OFF_BIAS);
    uint32_t* fl = reinterpret_cast<uint32_t*>(ws + OFF_FLAG);
    const int stride = gridDim.x * blockDim.x;
    const int tid0 = blockIdx.x * blockDim.x + threadIdx.x;

    // Wcat0 = [Whh0 | Wih0 | 0], row-major [1024][K0]
    for (int idx = tid0; idx < 1024 * K0; idx += stride) {
        int n = idx / K0, k = idx - n * K0;
        float ve, vd;
        if (k < 256)      { ve = eWhh0[n * 256 + k];       vd = dWhh0[n * 256 + k]; }
        else if (k < 264) { ve = eWih0[n * 8 + (k - 256)]; vd = dWih0[n * 8 + (k - 256)]; }
        else              { ve = 0.0f;                     vd = 0.0f; }
        W0e[idx] = __float2bfloat16(ve);
        W0d[idx] = __float2bfloat16(vd);
    }
    // Wcat1 = [Wih1 | Whh1], row-major [1024][512]
    for (int idx = tid0; idx < 1024 * 512; idx += stride) {
        int n = idx >> 9, k = idx & 511;
        float ve = (k < 256) ? eWih1[n * 256 + k] : eWhh1[n * 256 + (k - 256)];
        float vd = (k < 256) ? dWih1[n * 256 + k] : dWhh1[n * 256 + (k - 256)];
        W1e[idx] = __float2bfloat16(ve);
        W1d[idx] = __float2bfloat16(vd);
    }
    for (int idx = tid0; idx < 1024; idx += stride) {
        bias[idx]        = ebih0[idx] + ebhh0[idx];
        bias[1024 + idx] = ebih1[idx] + ebhh1[idx];
        bias[2048 + idx] = dbih0[idx] + dbhh0[idx];
        bias[3072 + idx] = dbih1[idx] + dbhh1[idx];
    }
    // zero sync flags (ws is re-poisoned 0xAA before every launch)
    for (int idx = tid0; idx < 256; idx += stride) fl[idx] = 0;
}

__global__ __launch_bounds__(512, 2) void lstm_kernel(
    const float* __restrict__ xc, const float* __restrict__ yc,
    const float* __restrict__ xt, const float* __restrict__ yt,
    const float* __restrict__ fcW, const float* __restrict__ fcb,
    unsigned char* __restrict__ ws, float* __restrict__ out)
{
    __shared__ __align__(16) __hip_bfloat16 HA[16][HAS]; // [h0(t) | x(t+1) | pad]
    __shared__ __align__(16) __hip_bfloat16 HB[16][HBS]; // [h1(t-1)]
    __shared__ float gsm0[2][4][16][16];                 // layer0 partials
    __shared__ float gsm1[2][4][16][16];                 // layer1 partials

    const int tid  = threadIdx.x;
    const int lane = tid & 63;
    const int wv   = tid >> 6;      // 0..7
    const int q    = wv & 3;        // gate quadrant (i,f,g,o)
    const int kh   = wv >> 2;       // K-half
    const int l15  = lane & 15;     // MFMA A-row (batch) / B-row (gate col)
    const int kg   = lane >> 4;     // k-group
    const int bg   = blockIdx.x >> 4;   // batch group 0..15
    const int ns   = blockIdx.x & 15;   // column slice 0..15

    const float* bias = (const float*)(ws + OFF_BIAS);
    uint32_t* flag = (uint32_t*)(ws + OFF_FLAG) + bg * 16;
    uint32_t* H32  = (uint32_t*)(ws + OFF_H);
    uint64_t* H64  = (uint64_t*)(ws + OFF_H);

    // ---- init LDS ----
    const __hip_bfloat16 z16 = __float2bfloat16(0.0f);
    for (int i = tid; i < 16 * HAS; i += 512) (&HA[0][0])[i] = z16;
    __syncthreads();
    if (tid < 128) {   // stage x(0)
        int r = tid >> 3, d = tid & 7, b = bg * 16 + r;
        float v = (d < 7) ? xc[(size_t)(b * T_CTXC) * 7 + d] : yc[b * T_CTXC];
        HA[r][256 + d] = __float2bfloat16(v);
    }

    // ---- weight slice in VGPRs: 13 B-fragments per lane ----
    bf16x8 w0f[5], w1f[8];
    const int wrow = q * 256 + ns * 16 + l15;
    auto load_w0 = [&](const __hip_bfloat16* W0) {
        const __hip_bfloat16* p0 = W0 + (size_t)wrow * K0 + kg * 8;
        if (kh == 0) {
            #pragma unroll
            for (int f = 0; f < 4; ++f) w0f[f] = *reinterpret_cast<const bf16x8*>(p0 + f * 32);
        } else {
            #pragma unroll
            for (int f = 0; f < 5; ++f) w0f[f] = *reinterpret_cast<const bf16x8*>(p0 + (4 + f) * 32);
        }
    };
    auto load_w1 = [&](const __hip_bfloat16* W1) {
        const __hip_bfloat16* p1 = W1 + (size_t)wrow * 512 + kg * 8;
        #pragma unroll
        for (int f = 0; f < 8; ++f)
            w1f[f] = *reinterpret_cast<const bf16x8*>(p1 + (kh * 8 + f) * 32);
    };
    load_w0((const __hip_bfloat16*)(ws + OFF_W0E));
    load_w1((const __hip_bfloat16*)(ws + OFF_W1E));

    // ---- per-cell-thread state (tid < 256: one (batch row, h col) each) ----
    const int crow = tid >> 4;
    const int ccol = tid & 15;
    const int gcol = ns * 16 + ccol;
    float c0v = 0.f, c1v = 0.f;
    float b0r[4] = {0,0,0,0}, b1r[4] = {0,0,0,0}, fcw_r = 0.f, fcb_v = 0.f;
    if (tid < 256) {
        #pragma unroll
        for (int qq = 0; qq < 4; ++qq) {
            b0r[qq] = bias[qq * 256 + gcol];
            b1r[qq] = bias[1024 + qq * 256 + gcol];
        }
        fcw_r = fcW[gcol];
        if (ns == 0) fcb_v = fcb[0];
    }
    __syncthreads();

    // ================= prologue: layer0(t=0) from h0(-1)=0 =================
    {
        f32x4 acc = {0.f, 0.f, 0.f, 0.f};
        if (kh == 0) {
            #pragma unroll
            for (int f = 0; f < 4; ++f) {
                bf16x8 a = *reinterpret_cast<const bf16x8*>(&HA[l15][f * 32 + kg * 8]);
                acc = __builtin_amdgcn_mfma_f32_16x16x32_bf16(a, w0f[f], acc, 0, 0, 0);
            }
        } else {
            #pragma unroll
            for (int f = 0; f < 5; ++f) {
                bf16x8 a = *reinterpret_cast<const bf16x8*>(&HA[l15][(4 + f) * 32 + kg * 8]);
                acc = __builtin_amdgcn_mfma_f32_16x16x32_bf16(a, w0f[f], acc, 0, 0, 0);
            }
        }
        #pragma unroll
        for (int r = 0; r < 4; ++r) gsm0[kh][q][kg * 4 + r][l15] = acc[r];
    }
    __syncthreads();
    if (tid < 256) {  // cell0(t=0) + publish {h0(0), h1(-1)=0} into parity 0
        float gi = gsm0[0][0][crow][ccol] + gsm0[1][0][crow][ccol] + b0r[0];
        float gf = gsm0[0][1][crow][ccol] + gsm0[1][1][crow][ccol] + b0r[1];
        float gg = gsm0[0][2][crow][ccol] + gsm0[1][2][crow][ccol] + b0r[2];
        float go = gsm0[0][3][crow][ccol] + gsm0[1][3][crow][ccol] + b0r[3];
        c0v = fsig(gf) * c0v + fsig(gi) * ftanh(gg);
        float h = fsig(go) * ftanh(c0v);
        __hip_bfloat16 hb = __float2bfloat16(h);
        unsigned short hbits; __builtin_memcpy(&hbits, &hb, 2);
        uint32_t hu = hbits;
        uint32_t pr = (uint32_t)__shfl_xor((int)hu, 1);
        if ((ccol & 1) == 0) {
            uint32_t v = (hu & 0xffffu) | (pr << 16);
            size_t base = ((size_t)bg * 32 + crow) * 128 + (gcol >> 1);   // parity 0
            __hip_atomic_store(&H32[base], v, __ATOMIC_RELAXED, __HIP_MEMORY_SCOPE_AGENT);
            __hip_atomic_store(&H32[base + 16 * 128], 0u,                  // h1(-1)=0
                               __ATOMIC_RELAXED, __HIP_MEMORY_SCOPE_AGENT);
        }
    }
    asm volatile("s_waitcnt vmcnt(0)" ::: "memory");
    __syncthreads();
    if (tid == 0)
        __hip_atomic_store(&flag[ns], 1u, __ATOMIC_RELAXED, __HIP_MEMORY_SCOPE_AGENT);

    // ================= main loop: iteration i computes layer1(i), layer0(i+1) ==
    for (int i = 0; i < TTOT; ++i) {
        const bool last = (i == TTOT - 1);
        if (i == T_CTXC - 1) {   // layer0 switches to decoder weights at t=512
            load_w0((const __hip_bfloat16*)(ws + OFF_W0D));
            if (tid < 256) {
                #pragma unroll
                for (int qq = 0; qq < 4; ++qq) b0r[qq] = bias[2048 + qq * 256 + gcol];
            }
        }
        if (i == T_CTXC) {       // layer1 switches at t=512
            load_w1((const __hip_bfloat16*)(ws + OFF_W1D));
            if (tid < 256) {
                #pragma unroll
                for (int qq = 0; qq < 4; ++qq) b1r[qq] = bias[3072 + qq * 256 + gcol];
            }
        }
        const int par = i & 1;

        // ---- phase 1: poll peers for {h0(i), h1(i-1)} ----
        if (tid < 16) {
            while (__hip_atomic_load(&flag[tid], __ATOMIC_RELAXED, __HIP_MEMORY_SCOPE_AGENT)
                   < (uint32_t)(i + 1))
                __builtin_amdgcn_s_sleep(1);
        }
        __syncthreads();

        // ---- phase 2: gather 16KB {h0 -> HA, h1 -> HB}; stage x(i+1) ----
        {
            int row = tid >> 4, cb = tid & 15;
            const uint64_t* src = H64 + ((size_t)(par * 16 + bg) * 32 + row) * 64 + cb * 4;
            uint64_t d0 = __hip_atomic_load(&src[0], __ATOMIC_RELAXED, __HIP_MEMORY_SCOPE_AGENT);
            uint64_t d1 = __hip_atomic_load(&src[1], __ATOMIC_RELAXED, __HIP_MEMORY_SCOPE_AGENT);
            uint64_t d2 = __hip_atomic_load(&src[2], __ATOMIC_RELAXED, __HIP_MEMORY_SCOPE_AGENT);
            uint64_t d3 = __hip_atomic_load(&src[3], __ATOMIC_RELAXED, __HIP_MEMORY_SCOPE_AGENT);
            uint4 v0 = make_uint4((uint32_t)d0, (uint32_t)(d0 >> 32),
                                  (uint32_t)d1, (uint32_t)(d1 >> 32));
            uint4 v1 = make_uint4((uint32_t)d2, (uint32_t)(d2 >> 32),
                                  (uint32_t)d3, (uint32_t)(d3 >> 32));
            if (row < 16) {
                *reinterpret_cast<uint4*>(&HA[row][cb * 16]) = v0;
                *reinterpret_cast<uint4*>(&HA[row][cb * 16 + 8]) = v1;
            } else {
                *reinterpret_cast<uint4*>(&HB[row - 16][cb * 16]) = v0;
                *reinterpret_cast<uint4*>(&HB[row - 16][cb * 16 + 8]) = v1;
            }
        }
        {
            int tn = i + 1;
            if (tid < 128 && tn < TTOT) {
                int r = tid >> 3, d = tid & 7, b = bg * 16 + r;
                float v;
                if (tn < T_CTXC)       v = (d < 7) ? xc[(size_t)(b * T_CTXC + tn) * 7 + d] : yc[b * T_CTXC + tn];
                else if (tn == T_CTXC) v = (d < 7) ? xc[(size_t)(b * T_CTXC + T_CTXC - 1) * 7 + d] : 0.0f;
                else { int u = tn - T_CTXC - 1;
                       v = (d < 7) ? xt[(size_t)(b * T_PRED + u) * 7 + d] : yt[b * T_PRED + u]; }
                HA[r][256 + d] = __float2bfloat16(v);
            }
        }
        __syncthreads();

        // ---- phase 3: layer1(i) GEMM [HA|HB] and layer0(i+1) GEMM [HA|x] ----
        {
            f32x4 acc = {0.f, 0.f, 0.f, 0.f};
            if (kh == 0) {
                #pragma unroll
                for (int f = 0; f < 8; ++f) {
                    bf16x8 a = *reinterpret_cast<const bf16x8*>(&HA[l15][f * 32 + kg * 8]);
                    acc = __builtin_amdgcn_mfma_f32_16x16x32_bf16(a, w1f[f], acc, 0, 0, 0);
                }
            } else {
                #pragma unroll
                for (int f = 0; f < 8; ++f) {
                    bf16x8 a = *reinterpret_cast<const bf16x8*>(&HB[l15][f * 32 + kg * 8]);
                    acc = __builtin_amdgcn_mfma_f32_16x16x32_bf16(a, w1f[f], acc, 0, 0, 0);
                }
            }
            #pragma unroll
            for (int r = 0; r < 4; ++r) gsm1[kh][q][kg * 4 + r][l15] = acc[r];
        }
        if (!last) {
            f32x4 acc = {0.f, 0.f, 0.f, 0.f};
            if (kh == 0) {
                #pragma unroll
                for (int f = 0; f < 4; ++f) {
                    bf16x8 a = *reinterpret_cast<const bf16x8*>(&HA[l15][f * 32 + kg * 8]);
                    acc = __builtin_amdgcn_mfma_f32_16x16x32_bf16(a, w0f[f], acc, 0, 0, 0);
                }
            } else {
                #pragma unroll
                for (int f = 0; f < 5; ++f) {
                    bf16x8 a = *reinterpret_cast<const bf16x8*>(&HA[l15][(4 + f) * 32 + kg * 8]);
                    acc = __builtin_amdgcn_mfma_f32_16x16x32_bf16(a, w0f[f], acc, 0, 0, 0);
                }
            }
            #pragma unroll
            for (int r = 0; r < 4; ++r) gsm0[kh][q][kg * 4 + r][l15] = acc[r];
        }
        __syncthreads();

        // ---- phase 4: cell updates + publish {h0(i+1), h1(i)} + output ----
        if (tid < 256) {
            const int par2 = (i + 1) & 1;
            const size_t base = ((size_t)(par2 * 16 + bg) * 32 + crow) * 128 + (gcol >> 1);
            // cell1(i)
            {
                float gi = gsm1[0][0][crow][ccol] + gsm1[1][0][crow][ccol] + b1r[0];
                float gf = gsm1[0][1][crow][ccol] + gsm1[1][1][crow][ccol] + b1r[1];
                float gg = gsm1[0][2][crow][ccol] + gsm1[1][2][crow][ccol] + b1r[2];
                float go = gsm1[0][3][crow][ccol] + gsm1[1][3][crow][ccol] + b1r[3];
                c1v = fsig(gf) * c1v + fsig(gi) * ftanh(gg);
                float h = fsig(go) * ftanh(c1v);
                if (!last) {
                    __hip_bfloat16 hb = __float2bfloat16(h);
                    unsigned short hbits; __builtin_memcpy(&hbits, &hb, 2);
                    uint32_t hu = hbits;
                    uint32_t pr = (uint32_t)__shfl_xor((int)hu, 1);
                    if ((ccol & 1) == 0) {
                        uint32_t v = (hu & 0xffffu) | (pr << 16);
                        __hip_atomic_store(&H32[base + 16 * 128], v,
                                           __ATOMIC_RELAXED, __HIP_MEMORY_SCOPE_AGENT);
                    }
                }
                if (i >= T_CTXC) {  // f32 output partial, atomicAdd into d_out
                    float p = h * fcw_r;
                    p += __shfl_xor(p, 1);
                    p += __shfl_xor(p, 2);
                    p += __shfl_xor(p, 4);
                    p += __shfl_xor(p, 8);
                    if (ccol == 0)
                        atomicAdd(&out[(size_t)(bg * 16 + crow) * T_PRED + (i - T_CTXC)],
                                  p + fcb_v);
                }
            }
            // cell0(i+1)
            if (!last) {
                float gi = gsm0[0][0][crow][ccol] + gsm0[1][0][crow][ccol] + b0r[0];
                float gf = gsm0[0][1][crow][ccol] + gsm0[1][1][crow][ccol] + b0r[1];
                float gg = gsm0[0][2][crow][ccol] + gsm0[1][2][crow][ccol] + b0r[2];
                float go = gsm0[0][3][crow][ccol] + gsm0[1][3][crow][ccol] + b0r[3];
                c0v = fsig(gf) * c0v + fsig(gi) * ftanh(gg);
                float h = fsig(go) * ftanh(c0v);
                __hip_bfloat16 hb = __float2bfloat16(h);
                unsigned short hbits; __builtin_memcpy(&hbits, &hb, 2);
                uint32_t hu = hbits;
                uint32_t pr = (uint32_t)__shfl_xor((int)hu, 1);
                if ((ccol & 1) == 0) {
                    uint32_t v = (hu & 0xffffu) | (pr << 16);
                    __hip_atomic_store(&H32[base], v,
                                       __ATOMIC_RELAXED, __HIP_MEMORY_SCOPE_AGENT);
                }
            }
        }
        if (!last) {
            asm volatile("s_waitcnt vmcnt(0)" ::: "memory");
            __syncthreads();
            if (tid == 0)
                __hip_atomic_store(&flag[ns], (uint32_t)(i + 2),
                                   __ATOMIC_RELAXED, __HIP_MEMORY_SCOPE_AGENT);
        }
    }
}

} // anonymous namespace

extern "C" void kernel_launch(void* const* d_in, const int* in_sizes, int n_in,
                              void* d_out, int out_size, void* d_ws, size_t ws_size,
                              hipStream_t stream)
{
    if (ws_size < WS_NEEDED) return;  // workspace too small (fails visibly)

    const float* xc    = (const float*)d_in[0];
    const float* yc    = (const float*)d_in[1];
    const float* xt    = (const float*)d_in[2];
    const float* yt    = (const float*)d_in[3];
    // d_in[4]: teacher_forcing_prob == 1 (decoder fully teacher-forced)
    const float* eWih0 = (const float*)d_in[5];
    const float* eWhh0 = (const float*)d_in[6];
    const float* ebih0 = (const float*)d_in[7];
    const float* ebhh0 = (const float*)d_in[8];
    const float* eWih1 = (const float*)d_in[9];
    const float* eWhh1 = (const float*)d_in[10];
    const float* ebih1 = (const float*)d_in[11];
    const float* ebhh1 = (const float*)d_in[12];
    const float* dWih0 = (const float*)d_in[13];
    const float* dWhh0 = (const float*)d_in[14];
    const float* dbih0 = (const float*)d_in[15];
    const float* dbhh0 = (const float*)d_in[16];
    const float* dWih1 = (const float*)d_in[17];
    const float* dWhh1 = (const float*)d_in[18];
    const float* dbih1 = (const float*)d_in[19];
    const float* dbhh1 = (const float*)d_in[20];
    const float* fcW   = (const float*)d_in[21];
    const float* fcb   = (const float*)d_in[22];

    unsigned char* wsb = (unsigned char*)d_ws;
    float* outp = (float*)d_out;

    hipLaunchKernelGGL(prep_kernel, dim3(1024), dim3(256), 0, stream,
                       eWih0, eWhh0, ebih0, ebhh0, eWih1, eWhh1, ebih1, ebhh1,
                       dWih0, dWhh0, dbih0, dbhh0, dWih1, dWhh1, dbih1, dbhh1, wsb);

    // output accumulated via atomicAdd -> zero it first
    hipMemsetAsync(d_out, 0, (size_t)out_size * sizeof(float), stream);

    // all 256 WGs must be co-resident (cross-WG flag waits) -> cooperative launch
    void* kargs[] = { (void*)&xc, (void*)&yc, (void*)&xt, (void*)&yt,
                      (void*)&fcW, (void*)&fcb, (void*)&wsb, (void*)&outp };
    hipError_t ce = hipLaunchCooperativeKernel(lstm_kernel, dim3(256), dim3(512),
                                               kargs, 0, stream);
    if (ce != hipSuccess) {
        // fallback: plain launch (256 WGs, ~35KB LDS, 1 WG/CU on 256 CUs)
        hipLaunchKernelGGL(lstm_kernel, dim3(256), dim3(512), 0, stream,
                           xc, yc, xt, yt, fcW, fcb, wsb, outp);
    }
}